// Round 15
// baseline (339.879 us; speedup 1.0000x reference)
//
#include <hip/hip_runtime.h>
#include <hip/hip_fp16.h>

// Problem constants (match reference setup_inputs()).
#define N_NODES 20000
#define E_EDGES 640000
// Layer dims: IN=256, H=8, HF=64, OUT=32

using half8_t = __attribute__((ext_vector_type(8))) _Float16;
using f32x4   = __attribute__((ext_vector_type(4))) float;

__device__ __forceinline__ void fma8(float acc[8], float w, const uint4& v) {
    const _Float16* hv = (const _Float16*)&v;
    #pragma unroll
    for (int c = 0; c < 8; ++c) acc[c] += w * (float)hv[c];
}

// ---------------------------------------------------------------------------
// CSR build: count (deg memset to 0 by host-side hipMemsetAsync), scan
// (adds +1 self-loop per node), scatter.
// ---------------------------------------------------------------------------
__global__ __launch_bounds__(256) void count_deg_kernel(const int* __restrict__ ei, int e,
                                                        int* __restrict__ deg) {
    int i = blockIdx.x * 256 + threadIdx.x;
    if (i < e) atomicAdd(&deg[ei[e + i]], 1);  // ei[1][i] = dst
}

// 1024 threads, each owns 20 contiguous elems (covers 20480 >= n).
// deg[] holds edge-counts only; +1 self-loop added here.
__global__ __launch_bounds__(1024) void scan_kernel(const int* __restrict__ deg,
                                                    int* __restrict__ row_start,
                                                    int* __restrict__ cursor,
                                                    int n, int total) {
    constexpr int PT = 20;
    __shared__ int wtot[16];
    const int t = threadIdx.x;
    const int lane = t & 63;
    const int wv = t >> 6;
    const int base = t * PT;
    int loc[PT];
    int s = 0;
    #pragma unroll
    for (int i = 0; i < PT; ++i) {
        int idx = base + i;
        int v = (idx < n) ? (deg[idx] + 1) : 0;   // +1 = self-loop
        loc[i] = s;
        s += v;
    }
    int x = s;
    #pragma unroll
    for (int off = 1; off < 64; off <<= 1) {
        int y = __shfl_up(x, off, 64);
        if (lane >= off) x += y;
    }
    if (lane == 63) wtot[wv] = x;
    __syncthreads();
    if (t < 16) {
        int w0 = wtot[t];
        int xx = w0;
        #pragma unroll
        for (int off = 1; off < 16; off <<= 1) {
            int y = __shfl_up(xx, off, 16);
            if (t >= off) xx += y;
        }
        wtot[t] = xx - w0;  // exclusive wave offset
    }
    __syncthreads();
    const int tstart = wtot[wv] + (x - s);
    #pragma unroll
    for (int i = 0; i < PT; ++i) {
        int idx = base + i;
        if (idx < n) {
            int v = tstart + loc[i];
            row_start[idx] = v;
            cursor[idx] = v;
        }
    }
    if (t == 0) row_start[n] = total;
}

__global__ __launch_bounds__(256) void scatter_kernel(const int* __restrict__ ei, int e, int n,
                                                      int* __restrict__ cursor,
                                                      int* __restrict__ csr_src) {
    int i = blockIdx.x * 256 + threadIdx.x;
    if (i >= e + n) return;
    int s, d;
    if (i < e) { s = ei[i]; d = ei[e + i]; }
    else       { s = i - e; d = s; }       // self-loop
    int slot = atomicAdd(&cursor[d], 1);
    csr_src[slot] = s;
}

// ---------------------------------------------------------------------------
// Cast kernels: x -> fp16; W -> fp16 transposed (row = output col).
// ---------------------------------------------------------------------------
__global__ __launch_bounds__(256) void cast_x_kernel(const float* __restrict__ x,
                                                     __half* __restrict__ xh, int total8) {
    int t = blockIdx.x * 256 + threadIdx.x;
    if (t >= total8) return;
    size_t o = (size_t)t * 8;
    float4 a = *(const float4*)&x[o];
    float4 b = *(const float4*)&x[o + 4];
    union { __half h[8]; uint4 u; } pk;
    pk.h[0] = __float2half(a.x); pk.h[1] = __float2half(a.y);
    pk.h[2] = __float2half(a.z); pk.h[3] = __float2half(a.w);
    pk.h[4] = __float2half(b.x); pk.h[5] = __float2half(b.y);
    pk.h[6] = __float2half(b.z); pk.h[7] = __float2half(b.w);
    *(uint4*)&xh[o] = pk.u;
}

// W[K][N] -> Wt[N][K] fp16.  grid.x = N, block = 256 (K <= 256 per call).
__global__ __launch_bounds__(256) void cast_wt_kernel(const float* __restrict__ W,
                                                      __half* __restrict__ Wt, int K, int N) {
    int nrow = blockIdx.x;
    int k = threadIdx.x;
    if (k < K) Wt[(size_t)nrow * K + k] = __float2half(W[(size_t)k * N + nrow]);
}

// ---------------------------------------------------------------------------
// fp16 MFMA GEMM + fused attention logits, v3: all-fp16 streaming.
// C[M,N] = A[M,K] @ B[K,N] with A fp16 [M][K] and B TRANSPOSED fp16 Bt[N][K].
// 128x128 block tile, 4 waves; wave w owns rows w*32..w*32+31 x 128 cols.
// Staging = pure uint4 copies (no convert, no transpose); LDA=LDB=40 keeps
// every LDS b128 access 16-B aligned.  Per k-step(32): 10 ds_read_b128 ->
// 16 v_mfma_f32_16x16x32_f16, fp32 accum.  Logits for the block's 128/CH
// heads fused from fp32 accumulators.
// ---------------------------------------------------------------------------
template <int CH>
__global__ __launch_bounds__(256) void gemm_kernel(const __half* __restrict__ A,
                                                   const __half* __restrict__ Bt,
                                                   __half* __restrict__ C,
                                                   const float* __restrict__ att_src,
                                                   const float* __restrict__ att_dst,
                                                   float* __restrict__ asrc_o,
                                                   float* __restrict__ adst_o,
                                                   int M, int K, int N) {
    constexpr int LDT = 40;  // LDS row stride in halves (32 + 8 pad, 80 B: 16-aligned)
    __shared__ __align__(16) _Float16 As[128 * LDT];  // 10240 B
    __shared__ __align__(16) _Float16 Bs[128 * LDT];  // 10240 B
    const int tid = threadIdx.x;
    const int bm = blockIdx.x * 128;
    const int bn = blockIdx.y * 128;
    const int w = tid >> 6;
    const int lane = tid & 63;
    const int l16 = lane & 15;
    const int quad = lane >> 4;
    const int s_r = tid >> 2;        // staging row 0..63 (two passes)
    const int s_c = tid & 3;         // 16-B chunk within the 64-B k-slice

    f32x4 acc[2][8];
    #pragma unroll
    for (int r = 0; r < 2; ++r)
        #pragma unroll
        for (int c = 0; c < 8; ++c) acc[r][c] = (f32x4){0.f, 0.f, 0.f, 0.f};

    for (int k0 = 0; k0 < K; k0 += 32) {
        // ---- stage A: 128 rows x 32 k (pure copy) ----
        #pragma unroll
        for (int pass = 0; pass < 2; ++pass) {
            const int row = s_r + pass * 64;
            const int gr = bm + row;
            uint4 av = make_uint4(0, 0, 0, 0);
            if (gr < M) av = *(const uint4*)&A[(size_t)gr * K + k0 + s_c * 8];
            *(uint4*)&As[row * LDT + s_c * 8] = av;
        }
        // ---- stage B: 128 n-rows x 32 k (pure copy) ----
        #pragma unroll
        for (int pass = 0; pass < 2; ++pass) {
            const int row = s_r + pass * 64;
            uint4 bv = *(const uint4*)&Bt[(size_t)(bn + row) * K + k0 + s_c * 8];
            *(uint4*)&Bs[row * LDT + s_c * 8] = bv;
        }
        __syncthreads();

        const half8_t af0 = *(const half8_t*)&As[(w * 32 + l16) * LDT + quad * 8];
        const half8_t af1 = *(const half8_t*)&As[(w * 32 + 16 + l16) * LDT + quad * 8];
        #pragma unroll
        for (int c = 0; c < 8; ++c) {
            const half8_t bf = *(const half8_t*)&Bs[(c * 16 + l16) * LDT + quad * 8];
            acc[0][c] = __builtin_amdgcn_mfma_f32_16x16x32_f16(af0, bf, acc[0][c], 0, 0, 0);
            acc[1][c] = __builtin_amdgcn_mfma_f32_16x16x32_f16(af1, bf, acc[1][c], 0, 0, 0);
        }
        __syncthreads();
    }

    // ---- C store (fp16) ----
    #pragma unroll
    for (int rf = 0; rf < 2; ++rf) {
        #pragma unroll
        for (int c = 0; c < 8; ++c) {
            #pragma unroll
            for (int r = 0; r < 4; ++r) {
                int row = bm + w * 32 + rf * 16 + quad * 4 + r;
                if (row < M)
                    C[(size_t)row * N + bn + c * 16 + l16] = __float2half(acc[rf][c][r]);
            }
        }
    }

    // ---- fused logits: block covers 128/CH full heads ----
    constexpr int HPB = 128 / CH;            // heads per block: 2 or 4
    constexpr int FPH = CH / 16;             // col-frags per head: 4 or 2
    const int hb0 = blockIdx.y * HPB;
    #pragma unroll
    for (int g = 0; g < HPB; ++g) {
        #pragma unroll
        for (int rf = 0; rf < 2; ++rf) {
            float ps[4] = {0.f, 0.f, 0.f, 0.f}, pd[4] = {0.f, 0.f, 0.f, 0.f};
            #pragma unroll
            for (int cc = 0; cc < FPH; ++cc) {
                const int c = g * FPH + cc;
                float av = att_src[(hb0 + g) * CH + cc * 16 + l16];
                float dv = att_dst[(hb0 + g) * CH + cc * 16 + l16];
                #pragma unroll
                for (int r = 0; r < 4; ++r) {
                    ps[r] += acc[rf][c][r] * av;
                    pd[r] += acc[rf][c][r] * dv;
                }
            }
            #pragma unroll
            for (int r = 0; r < 4; ++r) {
                #pragma unroll
                for (int off = 8; off; off >>= 1) {
                    ps[r] += __shfl_down(ps[r], off, 16);
                    pd[r] += __shfl_down(pd[r], off, 16);
                }
            }
            if (l16 == 0) {
                #pragma unroll
                for (int r = 0; r < 4; ++r) {
                    int row = bm + w * 32 + rf * 16 + quad * 4 + r;
                    if (row < M) {
                        asrc_o[row * 8 + hb0 + g] = ps[r];
                        adst_o[row * 8 + hb0 + g] = pd[r];
                    }
                }
            }
        }
    }
}

// ---------------------------------------------------------------------------
// Aggregation L1 (CH=64): 4 independent waves/block, wave = 8 dsts x 1 head,
// blockIdx = gg*8 + head for XCD locality; 2-stage pipelined gather.
// FROZEN: pinned at ~67 us across 3 structures = per-XCD L2 random-gather
// wall (676 MB / 8 XCDs / 1.26 TB/s-per-XCD).
// ---------------------------------------------------------------------------
__global__ __launch_bounds__(256) void aggregate1_kernel(const __half* __restrict__ h,
                                                         const float* __restrict__ asrc,
                                                         const float* __restrict__ adst,
                                                         const int* __restrict__ row_start,
                                                         const int* __restrict__ csr_src,
                                                         __half* __restrict__ partial) {
    constexpr int MAXD = 64;
    constexpr int LDE = 66;
    __shared__ __align__(16) uint2 s_oe[4][8 * LDE];  // 16896 B
    const int head = blockIdx.x & 7;
    const int gg = blockIdx.x >> 3;
    const int wv = threadIdx.x >> 6;
    const int lane = threadIdx.x & 63;
    const int d = lane >> 3;
    const int il = lane & 7;
    const int i = (gg * 4 + wv) * 8 + d;
    const int start = row_start[i];
    const int deg = row_start[i + 1] - start;
    const float ad = adst[i * 8 + head];
    const bool fast = (deg <= MAXD);

    float lsum = 0.f;
    for (int k = il; k < deg; k += 8) {
        int j = csr_src[start + k];
        float e = asrc[j * 8 + head] + ad;
        e = e > 0.f ? e : 0.2f * e;
        float ex = __expf(e);
        if (fast)
            s_oe[wv][d * LDE + k] = make_uint2((unsigned)(j * 1024), __float_as_uint(ex));
        lsum += ex;
    }
    lsum += __shfl_xor(lsum, 1, 64);
    lsum += __shfl_xor(lsum, 2, 64);
    lsum += __shfl_xor(lsum, 4, 64);
    const float dinv = 1.0f / lsum;
    __syncthreads();

    const int c0 = il * 8;
    const char* __restrict__ hb = (const char*)h + (head * 64 + c0) * 2;
    float acc[8];
    #pragma unroll
    for (int c = 0; c < 8; ++c) acc[c] = 0.f;

    if (fast) {
        const uint2* __restrict__ row = &s_oe[wv][d * LDE];
        int k = 0;
        if (deg >= 8) {
            uint4 q0 = *(const uint4*)&row[0];
            uint4 q1 = *(const uint4*)&row[2];
            uint4 v0 = *(const uint4*)(hb + q0.x);
            uint4 v1 = *(const uint4*)(hb + q0.z);
            uint4 v2 = *(const uint4*)(hb + q1.x);
            uint4 v3 = *(const uint4*)(hb + q1.z);
            for (k = 4; k + 3 < deg; k += 4) {
                uint4 nq0 = *(const uint4*)&row[k];
                uint4 nq1 = *(const uint4*)&row[k + 2];
                uint4 nv0 = *(const uint4*)(hb + nq0.x);
                uint4 nv1 = *(const uint4*)(hb + nq0.z);
                uint4 nv2 = *(const uint4*)(hb + nq1.x);
                uint4 nv3 = *(const uint4*)(hb + nq1.z);
                fma8(acc, __uint_as_float(q0.y), v0);
                fma8(acc, __uint_as_float(q0.w), v1);
                fma8(acc, __uint_as_float(q1.y), v2);
                fma8(acc, __uint_as_float(q1.w), v3);
                q0 = nq0; q1 = nq1; v0 = nv0; v1 = nv1; v2 = nv2; v3 = nv3;
            }
            fma8(acc, __uint_as_float(q0.y), v0);
            fma8(acc, __uint_as_float(q0.w), v1);
            fma8(acc, __uint_as_float(q1.y), v2);
            fma8(acc, __uint_as_float(q1.w), v3);
        }
        for (; k < deg; ++k) {
            uint2 oe = row[k];
            uint4 v = *(const uint4*)(hb + oe.x);
            fma8(acc, __uint_as_float(oe.y), v);
        }
    } else {
        for (int k = 0; k < deg; ++k) {
            int j = csr_src[start + k];
            float e = asrc[j * 8 + head] + ad;
            e = e > 0.f ? e : 0.2f * e;
            uint4 v = *(const uint4*)(hb + (size_t)j * 1024);
            fma8(acc, __expf(e), v);
        }
    }

    union { __half h8[8]; uint4 u4; } pk;
    #pragma unroll
    for (int c = 0; c < 8; ++c) pk.h8[c] = __float2half(acc[c] * dinv);
    *(uint4*)&partial[((size_t)i * 8 + head) * 64 + c0] = pk.u4;
}

// ---------------------------------------------------------------------------
// Aggregation L2 (CH=32): one wave = 8 dsts x 2 heads (pair p = blockIdx&3,
// XCDs {p, p+4}); both heads' exps packed half2 in LDS; pipelined gather.
// ---------------------------------------------------------------------------
__global__ __launch_bounds__(256) void aggregate2_kernel(const __half* __restrict__ h,
                                                         const float* __restrict__ asrc,
                                                         const float* __restrict__ adst,
                                                         const int* __restrict__ row_start,
                                                         const int* __restrict__ csr_src,
                                                         __half* __restrict__ partial) {
    constexpr int MAXD = 64;
    constexpr int LDE = 66;
    __shared__ __align__(16) uint2 s_oe[4][8 * LDE];  // 16896 B
    const int b = blockIdx.x;
    const int p = b & 3;
    const int g = b >> 2;
    const int wv = threadIdx.x >> 6;
    const int lane = threadIdx.x & 63;
    const int d = lane >> 3;
    const int il = lane & 7;
    const int hsel = il >> 2;
    const int cl = il & 3;
    const int head = p * 2 + hsel;
    const int i = g * 32 + wv * 8 + d;
    const int start = row_start[i];
    const int deg = row_start[i + 1] - start;
    const float2 adp = *(const float2*)&adst[i * 8 + p * 2];
    const bool fast = (deg <= MAXD);

    float lsum0 = 0.f, lsum1 = 0.f;
    for (int k = il; k < deg; k += 8) {
        int j = csr_src[start + k];
        float2 as = *(const float2*)&asrc[j * 8 + p * 2];
        float e0 = as.x + adp.x; e0 = e0 > 0.f ? e0 : 0.2f * e0;
        float e1 = as.y + adp.y; e1 = e1 > 0.f ? e1 : 0.2f * e1;
        union { __half hh; unsigned short u; } x0, x1;
        x0.hh = __float2half(__expf(e0));
        x1.hh = __float2half(__expf(e1));
        if (fast)
            s_oe[wv][d * LDE + k] =
                make_uint2((unsigned)(j * 512), ((unsigned)x1.u << 16) | x0.u);
        lsum0 += __half2float(x0.hh);
        lsum1 += __half2float(x1.hh);
    }
    lsum0 += __shfl_xor(lsum0, 1, 64); lsum1 += __shfl_xor(lsum1, 1, 64);
    lsum0 += __shfl_xor(lsum0, 2, 64); lsum1 += __shfl_xor(lsum1, 2, 64);
    lsum0 += __shfl_xor(lsum0, 4, 64); lsum1 += __shfl_xor(lsum1, 4, 64);
    const float dinv = 1.0f / (hsel ? lsum1 : lsum0);
    __syncthreads();

    const int sh = hsel * 16;
    const char* __restrict__ hb = (const char*)h + head * 64 + cl * 16;
    float acc[8];
    #pragma unroll
    for (int c = 0; c < 8; ++c) acc[c] = 0.f;

    auto hw = [&](unsigned packed) -> float {
        union { unsigned short u; __half hh; } cv;
        cv.u = (unsigned short)(packed >> sh);
        return __half2float(cv.hh);
    };

    if (fast) {
        const uint2* __restrict__ row = &s_oe[wv][d * LDE];
        int k = 0;
        if (deg >= 8) {
            uint4 q0 = *(const uint4*)&row[0];
            uint4 q1 = *(const uint4*)&row[2];
            uint4 v0 = *(const uint4*)(hb + q0.x);
            uint4 v1 = *(const uint4*)(hb + q0.z);
            uint4 v2 = *(const uint4*)(hb + q1.x);
            uint4 v3 = *(const uint4*)(hb + q1.z);
            for (k = 4; k + 3 < deg; k += 4) {
                uint4 nq0 = *(const uint4*)&row[k];
                uint4 nq1 = *(const uint4*)&row[k + 2];
                uint4 nv0 = *(const uint4*)(hb + nq0.x);
                uint4 nv1 = *(const uint4*)(hb + nq0.z);
                uint4 nv2 = *(const uint4*)(hb + nq1.x);
                uint4 nv3 = *(const uint4*)(hb + nq1.z);
                fma8(acc, hw(q0.y), v0);
                fma8(acc, hw(q0.w), v1);
                fma8(acc, hw(q1.y), v2);
                fma8(acc, hw(q1.w), v3);
                q0 = nq0; q1 = nq1; v0 = nv0; v1 = nv1; v2 = nv2; v3 = nv3;
            }
            fma8(acc, hw(q0.y), v0);
            fma8(acc, hw(q0.w), v1);
            fma8(acc, hw(q1.y), v2);
            fma8(acc, hw(q1.w), v3);
        }
        for (; k < deg; ++k) {
            uint2 oe = row[k];
            uint4 v = *(const uint4*)(hb + oe.x);
            fma8(acc, hw(oe.y), v);
        }
    } else {
        const float adh = hsel ? adp.y : adp.x;
        for (int k = 0; k < deg; ++k) {
            int j = csr_src[start + k];
            float e = asrc[j * 8 + head] + adh;
            e = e > 0.f ? e : 0.2f * e;
            uint4 v = *(const uint4*)(hb + (size_t)j * 512);
            fma8(acc, __expf(e), v);
        }
    }

    union { __half h8[8]; uint4 u4; } pk;
    #pragma unroll
    for (int c = 0; c < 8; ++c) pk.h8[c] = __float2half(acc[c] * dinv);
    *(uint4*)&partial[((size_t)i * 8 + head) * 32 + cl * 8] = pk.u4;
}

// ---------------------------------------------------------------------------
// Merge heads: out = [relu](mean_h partial + bias); fp16 or fp32 output.
// ---------------------------------------------------------------------------
template <int CH, bool RELU, bool HALF_OUT>
__global__ __launch_bounds__(256) void merge_kernel(const __half* __restrict__ partial,
                                                    const float* __restrict__ bias,
                                                    void* __restrict__ out) {
    int flat = blockIdx.x * 256 + threadIdx.x;
    int i = flat / CH;
    int c = flat % CH;
    float s = 0.f;
    #pragma unroll
    for (int h8 = 0; h8 < 8; ++h8)
        s += __half2float(partial[((size_t)i * 8 + h8) * CH + c]);
    s = s * 0.125f + bias[c];
    if (RELU) s = fmaxf(s, 0.f);
    if (HALF_OUT) ((__half*)out)[flat] = __float2half(s);
    else          ((float*)out)[flat] = s;
}

// ---------------------------------------------------------------------------
// Launch
// ---------------------------------------------------------------------------
extern "C" void kernel_launch(void* const* d_in, const int* in_sizes, int n_in,
                              void* d_out, int out_size, void* d_ws, size_t ws_size,
                              hipStream_t stream) {
    const float* x   = (const float*)d_in[0];
    const int*   ei  = (const int*)d_in[1];
    const float* W1  = (const float*)d_in[2];
    const float* as1 = (const float*)d_in[3];
    const float* ad1 = (const float*)d_in[4];
    const float* b1  = (const float*)d_in[5];
    const float* W2  = (const float*)d_in[6];
    const float* as2 = (const float*)d_in[7];
    const float* ad2 = (const float*)d_in[8];
    const float* b2  = (const float*)d_in[9];

    const int n = N_NODES;
    const int e = E_EDGES;

    // ---- workspace layout ----
    char* w = (char*)d_ws;
    __half* partial = (__half*)w; w += (size_t)n * 8 * 64 * 2;  // 20.48 MB
    __half* h_buf = (__half*)w; w += (size_t)n * 512 * 2;       // 20.48 MB
    __half* xh    = (__half*)w; w += (size_t)n * 256 * 2;       // 10.24 MB
    __half* y1h   = (__half*)w; w += (size_t)n * 64 * 2;        // 2.56 MB
    __half* w1t   = (__half*)w; w += (size_t)512 * 256 * 2;     // 256 KB
    __half* w2t   = (__half*)w; w += (size_t)256 * 64 * 2;      // 32 KB
    float* asrc   = (float*)w; w += (size_t)n * 8 * 4;
    float* adst   = (float*)w; w += (size_t)n * 8 * 4;
    int* deg       = (int*)w; w += (size_t)n * 4;
    int* row_start = (int*)w; w += (size_t)(n + 1) * 4;
    int* cursor    = (int*)w; w += (size_t)n * 4;
    int* csr_src   = (int*)w; w += (size_t)(e + n) * 4;

    // ---- CSR build (graph identical for both layers) ----
    hipMemsetAsync(deg, 0, (size_t)n * 4, stream);
    count_deg_kernel<<<(e + 255) / 256, 256, 0, stream>>>(ei, e, deg);
    scan_kernel<<<1, 1024, 0, stream>>>(deg, row_start, cursor, n, e + n);
    scatter_kernel<<<(e + n + 255) / 256, 256, 0, stream>>>(ei, e, n, cursor, csr_src);

    // ---- one-time fp16 casts ----
    cast_x_kernel<<<(n * 256 / 8 + 255) / 256, 256, 0, stream>>>(x, xh, n * 256 / 8);
    cast_wt_kernel<<<512, 256, 0, stream>>>(W1, w1t, 256, 512);
    cast_wt_kernel<<<256, 256, 0, stream>>>(W2, w2t, 64, 256);

    const int mb = (n + 127) / 128;  // 157

    // ---- Layer 1 (logits fused into GEMM, 128x128 tiles, all-fp16 stream) ----
    gemm_kernel<64><<<dim3(mb, 4), 256, 0, stream>>>(
        xh, w1t, h_buf, as1, ad1, asrc, adst, n, 256, 512);
    aggregate1_kernel<<<(n / 32) * 8, 256, 0, stream>>>(h_buf, asrc, adst, row_start,
                                                        csr_src, partial);
    merge_kernel<64, true, true><<<n * 64 / 256, 256, 0, stream>>>(partial, b1, y1h);

    // ---- Layer 2 ----
    gemm_kernel<32><<<dim3(mb, 2), 256, 0, stream>>>(
        y1h, w2t, h_buf, as2, ad2, asrc, adst, n, 64, 256);
    aggregate2_kernel<<<(n / 32) * 4, 256, 0, stream>>>(h_buf, asrc, adst, row_start,
                                                        csr_src, partial);
    merge_kernel<32, false, false><<<n * 32 / 256, 256, 0, stream>>>(partial, b2, (float*)d_out);
}

// Round 16
// 329.725 us; speedup vs baseline: 1.0308x; 1.0308x over previous
//
#include <hip/hip_runtime.h>
#include <hip/hip_fp16.h>

// Problem constants (match reference setup_inputs()).
#define N_NODES 20000
#define E_EDGES 640000
// Layer dims: IN=256, H=8, HF=64, OUT=32

using half8_t = __attribute__((ext_vector_type(8))) _Float16;
using f32x4   = __attribute__((ext_vector_type(4))) float;

__device__ __forceinline__ void fma8(float acc[8], float w, const uint4& v) {
    const _Float16* hv = (const _Float16*)&v;
    #pragma unroll
    for (int c = 0; c < 8; ++c) acc[c] += w * (float)hv[c];
}

// ---------------------------------------------------------------------------
// CSR build: deg init (self-loop counts as 1), count, scan, scatter
// ---------------------------------------------------------------------------
__global__ __launch_bounds__(256) void init_deg_kernel(int* __restrict__ deg, int n) {
    int i = blockIdx.x * 256 + threadIdx.x;
    if (i < n) deg[i] = 1;
}

__global__ __launch_bounds__(256) void count_deg_kernel(const int* __restrict__ ei, int e,
                                                        int* __restrict__ deg) {
    int i = blockIdx.x * 256 + threadIdx.x;
    if (i < e) atomicAdd(&deg[ei[e + i]], 1);  // ei[1][i] = dst
}

// 1024 threads, each owns 20 contiguous elems (covers 20480 >= n).
__global__ __launch_bounds__(1024) void scan_kernel(const int* __restrict__ deg,
                                                    int* __restrict__ row_start,
                                                    int* __restrict__ cursor,
                                                    int n, int total) {
    constexpr int PT = 20;
    __shared__ int wtot[16];
    const int t = threadIdx.x;
    const int lane = t & 63;
    const int wv = t >> 6;
    const int base = t * PT;
    int loc[PT];
    int s = 0;
    #pragma unroll
    for (int i = 0; i < PT; ++i) {
        int idx = base + i;
        int v = (idx < n) ? deg[idx] : 0;
        loc[i] = s;
        s += v;
    }
    int x = s;
    #pragma unroll
    for (int off = 1; off < 64; off <<= 1) {
        int y = __shfl_up(x, off, 64);
        if (lane >= off) x += y;
    }
    if (lane == 63) wtot[wv] = x;
    __syncthreads();
    if (t < 16) {
        int w0 = wtot[t];
        int xx = w0;
        #pragma unroll
        for (int off = 1; off < 16; off <<= 1) {
            int y = __shfl_up(xx, off, 16);
            if (t >= off) xx += y;
        }
        wtot[t] = xx - w0;  // exclusive wave offset
    }
    __syncthreads();
    const int tstart = wtot[wv] + (x - s);
    #pragma unroll
    for (int i = 0; i < PT; ++i) {
        int idx = base + i;
        if (idx < n) {
            int v = tstart + loc[i];
            row_start[idx] = v;
            cursor[idx] = v;
        }
    }
    if (t == 0) row_start[n] = total;
}

__global__ __launch_bounds__(256) void scatter_kernel(const int* __restrict__ ei, int e, int n,
                                                      int* __restrict__ cursor,
                                                      int* __restrict__ csr_src) {
    int i = blockIdx.x * 256 + threadIdx.x;
    if (i >= e + n) return;
    int s, d;
    if (i < e) { s = ei[i]; d = ei[e + i]; }
    else       { s = i - e; d = s; }       // self-loop
    int slot = atomicAdd(&cursor[d], 1);
    csr_src[slot] = s;
}

// ---------------------------------------------------------------------------
// MFMA GEMM + fused attention logits: 128x128 block tile.  A fp32 (cast in
// staging) or fp16 (pure copy) via template; W fp32, transposed in LDS.
// 4 waves; wave w owns rows w*32..w*32+31 x 128 cols: acc = 2x8 f32x4.
// Per k-step(32): 10 ds_read_b128 -> 16 MFMA.  Logits for the block's
// 128/CH heads fused from the fp32 accumulators.
// ---------------------------------------------------------------------------
template <int CH, typename AT>
__global__ __launch_bounds__(256) void gemm_kernel(const AT* __restrict__ A,
                                                   const float* __restrict__ W,
                                                   __half* __restrict__ C,
                                                   const float* __restrict__ att_src,
                                                   const float* __restrict__ att_dst,
                                                   float* __restrict__ asrc_o,
                                                   float* __restrict__ adst_o,
                                                   int M, int K, int N) {
    constexpr int LDA = 40;  // As row stride in halves (32 + 8 pad)
    constexpr int LDB = 34;  // Bs row stride in halves (32 + 2 pad)
    __shared__ __align__(16) _Float16 As[128 * LDA];  // 10240 B
    __shared__ __align__(16) _Float16 Bs[128 * LDB];  //  8704 B
    const int tid = threadIdx.x;
    const int bm = blockIdx.x * 128;
    const int bn = blockIdx.y * 128;
    const int w = tid >> 6;
    const int lane = tid & 63;
    const int l16 = lane & 15;
    const int quad = lane >> 4;

    f32x4 acc[2][8];
    #pragma unroll
    for (int r = 0; r < 2; ++r)
        #pragma unroll
        for (int c = 0; c < 8; ++c) acc[r][c] = (f32x4){0.f, 0.f, 0.f, 0.f};

    for (int k0 = 0; k0 < K; k0 += 32) {
        // ---- stage A: 128 rows x 32 k ----
        if constexpr (sizeof(AT) == 4) {
            const int a_r = tid >> 3;          // 32 rows per pass
            const int a_k4 = (tid & 7) * 4;
            #pragma unroll
            for (int rr = 0; rr < 4; ++rr) {
                const int row = a_r + rr * 32;
                const int gr = bm + row;
                float4 av = make_float4(0.f, 0.f, 0.f, 0.f);
                if (gr < M) av = *(const float4*)&A[(size_t)gr * K + k0 + a_k4];
                union { __half h[4]; uint2 u; } pk;
                pk.h[0] = __float2half(av.x); pk.h[1] = __float2half(av.y);
                pk.h[2] = __float2half(av.z); pk.h[3] = __float2half(av.w);
                *(uint2*)&As[row * LDA + a_k4] = pk.u;
            }
        } else {
            const int a_r = tid >> 2;          // 64 rows per pass
            const int a_k8 = (tid & 3) * 8;
            #pragma unroll
            for (int rr = 0; rr < 2; ++rr) {
                const int row = a_r + rr * 64;
                const int gr = bm + row;
                uint4 av = make_uint4(0, 0, 0, 0);
                if (gr < M) av = *(const uint4*)&A[(size_t)gr * K + k0 + a_k8];
                *(uint4*)&As[row * LDA + a_k8] = av;
            }
        }
        // ---- stage B: 32 k x 128 n, fp32 -> fp16, transposed to [n][k] ----
        {
            const int b_kr = tid >> 5;         // 8 k-rows per pass
            const int b_n4 = (tid & 31) * 4;
            #pragma unroll
            for (int pass = 0; pass < 4; ++pass) {
                const int kr = b_kr + pass * 8;
                float4 wv = *(const float4*)&W[(size_t)(k0 + kr) * N + bn + b_n4];
                Bs[(b_n4 + 0) * LDB + kr] = (_Float16)wv.x;
                Bs[(b_n4 + 1) * LDB + kr] = (_Float16)wv.y;
                Bs[(b_n4 + 2) * LDB + kr] = (_Float16)wv.z;
                Bs[(b_n4 + 3) * LDB + kr] = (_Float16)wv.w;
            }
        }
        __syncthreads();

        const half8_t af0 = *(const half8_t*)&As[(w * 32 + l16) * LDA + quad * 8];
        const half8_t af1 = *(const half8_t*)&As[(w * 32 + 16 + l16) * LDA + quad * 8];
        #pragma unroll
        for (int c = 0; c < 8; ++c) {
            const half8_t bf = *(const half8_t*)&Bs[(c * 16 + l16) * LDB + quad * 8];
            acc[0][c] = __builtin_amdgcn_mfma_f32_16x16x32_f16(af0, bf, acc[0][c], 0, 0, 0);
            acc[1][c] = __builtin_amdgcn_mfma_f32_16x16x32_f16(af1, bf, acc[1][c], 0, 0, 0);
        }
        __syncthreads();
    }

    // ---- C store (fp16) ----
    #pragma unroll
    for (int rf = 0; rf < 2; ++rf) {
        #pragma unroll
        for (int c = 0; c < 8; ++c) {
            #pragma unroll
            for (int r = 0; r < 4; ++r) {
                int row = bm + w * 32 + rf * 16 + quad * 4 + r;
                if (row < M)
                    C[(size_t)row * N + bn + c * 16 + l16] = __float2half(acc[rf][c][r]);
            }
        }
    }

    // ---- fused logits: block covers 128/CH full heads ----
    constexpr int HPB = 128 / CH;            // heads per block: 2 or 4
    constexpr int FPH = CH / 16;             // col-frags per head: 4 or 2
    const int hb0 = blockIdx.y * HPB;
    #pragma unroll
    for (int g = 0; g < HPB; ++g) {
        #pragma unroll
        for (int rf = 0; rf < 2; ++rf) {
            float ps[4] = {0.f, 0.f, 0.f, 0.f}, pd[4] = {0.f, 0.f, 0.f, 0.f};
            #pragma unroll
            for (int cc = 0; cc < FPH; ++cc) {
                const int c = g * FPH + cc;
                float av = att_src[(hb0 + g) * CH + cc * 16 + l16];
                float dv = att_dst[(hb0 + g) * CH + cc * 16 + l16];
                #pragma unroll
                for (int r = 0; r < 4; ++r) {
                    ps[r] += acc[rf][c][r] * av;
                    pd[r] += acc[rf][c][r] * dv;
                }
            }
            #pragma unroll
            for (int r = 0; r < 4; ++r) {
                #pragma unroll
                for (int off = 8; off; off >>= 1) {
                    ps[r] += __shfl_down(ps[r], off, 16);
                    pd[r] += __shfl_down(pd[r], off, 16);
                }
            }
            if (l16 == 0) {
                #pragma unroll
                for (int r = 0; r < 4; ++r) {
                    int row = bm + w * 32 + rf * 16 + quad * 4 + r;
                    if (row < M) {
                        asrc_o[row * 8 + hb0 + g] = ps[r];
                        adst_o[row * 8 + hb0 + g] = pd[r];
                    }
                }
            }
        }
    }
}

// ---------------------------------------------------------------------------
// Aggregation L1 (CH=64): 4 independent waves/block, wave = 8 dsts x 1 head,
// blockIdx = gg*8 + head for XCD locality; 2-stage pipelined gather.
// FROZEN: pinned at ~67 us across 3 structures = per-XCD L2 random-gather
// wall (676 MB / 8 XCDs / ~1.26 TB/s-per-XCD).
// ---------------------------------------------------------------------------
__global__ __launch_bounds__(256) void aggregate1_kernel(const __half* __restrict__ h,
                                                         const float* __restrict__ asrc,
                                                         const float* __restrict__ adst,
                                                         const int* __restrict__ row_start,
                                                         const int* __restrict__ csr_src,
                                                         __half* __restrict__ partial) {
    constexpr int MAXD = 64;
    constexpr int LDE = 66;
    __shared__ __align__(16) uint2 s_oe[4][8 * LDE];  // 16896 B
    const int head = blockIdx.x & 7;
    const int gg = blockIdx.x >> 3;
    const int wv = threadIdx.x >> 6;
    const int lane = threadIdx.x & 63;
    const int d = lane >> 3;
    const int il = lane & 7;
    const int i = (gg * 4 + wv) * 8 + d;
    const int start = row_start[i];
    const int deg = row_start[i + 1] - start;
    const float ad = adst[i * 8 + head];
    const bool fast = (deg <= MAXD);

    float lsum = 0.f;
    for (int k = il; k < deg; k += 8) {
        int j = csr_src[start + k];
        float e = asrc[j * 8 + head] + ad;
        e = e > 0.f ? e : 0.2f * e;
        float ex = __expf(e);
        if (fast)
            s_oe[wv][d * LDE + k] = make_uint2((unsigned)(j * 1024), __float_as_uint(ex));
        lsum += ex;
    }
    lsum += __shfl_xor(lsum, 1, 64);
    lsum += __shfl_xor(lsum, 2, 64);
    lsum += __shfl_xor(lsum, 4, 64);
    const float dinv = 1.0f / lsum;
    __syncthreads();

    const int c0 = il * 8;
    const char* __restrict__ hb = (const char*)h + (head * 64 + c0) * 2;
    float acc[8];
    #pragma unroll
    for (int c = 0; c < 8; ++c) acc[c] = 0.f;

    if (fast) {
        const uint2* __restrict__ row = &s_oe[wv][d * LDE];
        int k = 0;
        if (deg >= 8) {
            uint4 q0 = *(const uint4*)&row[0];
            uint4 q1 = *(const uint4*)&row[2];
            uint4 v0 = *(const uint4*)(hb + q0.x);
            uint4 v1 = *(const uint4*)(hb + q0.z);
            uint4 v2 = *(const uint4*)(hb + q1.x);
            uint4 v3 = *(const uint4*)(hb + q1.z);
            for (k = 4; k + 3 < deg; k += 4) {
                uint4 nq0 = *(const uint4*)&row[k];
                uint4 nq1 = *(const uint4*)&row[k + 2];
                uint4 nv0 = *(const uint4*)(hb + nq0.x);
                uint4 nv1 = *(const uint4*)(hb + nq0.z);
                uint4 nv2 = *(const uint4*)(hb + nq1.x);
                uint4 nv3 = *(const uint4*)(hb + nq1.z);
                fma8(acc, __uint_as_float(q0.y), v0);
                fma8(acc, __uint_as_float(q0.w), v1);
                fma8(acc, __uint_as_float(q1.y), v2);
                fma8(acc, __uint_as_float(q1.w), v3);
                q0 = nq0; q1 = nq1; v0 = nv0; v1 = nv1; v2 = nv2; v3 = nv3;
            }
            fma8(acc, __uint_as_float(q0.y), v0);
            fma8(acc, __uint_as_float(q0.w), v1);
            fma8(acc, __uint_as_float(q1.y), v2);
            fma8(acc, __uint_as_float(q1.w), v3);
        }
        for (; k < deg; ++k) {
            uint2 oe = row[k];
            uint4 v = *(const uint4*)(hb + oe.x);
            fma8(acc, __uint_as_float(oe.y), v);
        }
    } else {
        for (int k = 0; k < deg; ++k) {
            int j = csr_src[start + k];
            float e = asrc[j * 8 + head] + ad;
            e = e > 0.f ? e : 0.2f * e;
            uint4 v = *(const uint4*)(hb + (size_t)j * 1024);
            fma8(acc, __expf(e), v);
        }
    }

    union { __half h8[8]; uint4 u4; } pk;
    #pragma unroll
    for (int c = 0; c < 8; ++c) pk.h8[c] = __float2half(acc[c] * dinv);
    *(uint4*)&partial[((size_t)i * 8 + head) * 64 + c0] = pk.u4;
}

// ---------------------------------------------------------------------------
// Aggregation L2 (CH=32): one wave = 8 dsts x 2 heads (pair p = blockIdx&3,
// XCDs {p, p+4}); both heads' exps packed half2 in LDS; pipelined gather.
// ---------------------------------------------------------------------------
__global__ __launch_bounds__(256) void aggregate2_kernel(const __half* __restrict__ h,
                                                         const float* __restrict__ asrc,
                                                         const float* __restrict__ adst,
                                                         const int* __restrict__ row_start,
                                                         const int* __restrict__ csr_src,
                                                         __half* __restrict__ partial) {
    constexpr int MAXD = 64;
    constexpr int LDE = 66;
    __shared__ __align__(16) uint2 s_oe[4][8 * LDE];  // 16896 B
    const int b = blockIdx.x;
    const int p = b & 3;
    const int g = b >> 2;
    const int wv = threadIdx.x >> 6;
    const int lane = threadIdx.x & 63;
    const int d = lane >> 3;
    const int il = lane & 7;
    const int hsel = il >> 2;
    const int cl = il & 3;
    const int head = p * 2 + hsel;
    const int i = g * 32 + wv * 8 + d;
    const int start = row_start[i];
    const int deg = row_start[i + 1] - start;
    const float2 adp = *(const float2*)&adst[i * 8 + p * 2];
    const bool fast = (deg <= MAXD);

    float lsum0 = 0.f, lsum1 = 0.f;
    for (int k = il; k < deg; k += 8) {
        int j = csr_src[start + k];
        float2 as = *(const float2*)&asrc[j * 8 + p * 2];
        float e0 = as.x + adp.x; e0 = e0 > 0.f ? e0 : 0.2f * e0;
        float e1 = as.y + adp.y; e1 = e1 > 0.f ? e1 : 0.2f * e1;
        union { __half hh; unsigned short u; } x0, x1;
        x0.hh = __float2half(__expf(e0));
        x1.hh = __float2half(__expf(e1));
        if (fast)
            s_oe[wv][d * LDE + k] =
                make_uint2((unsigned)(j * 512), ((unsigned)x1.u << 16) | x0.u);
        lsum0 += __half2float(x0.hh);
        lsum1 += __half2float(x1.hh);
    }
    lsum0 += __shfl_xor(lsum0, 1, 64); lsum1 += __shfl_xor(lsum1, 1, 64);
    lsum0 += __shfl_xor(lsum0, 2, 64); lsum1 += __shfl_xor(lsum1, 2, 64);
    lsum0 += __shfl_xor(lsum0, 4, 64); lsum1 += __shfl_xor(lsum1, 4, 64);
    const float dinv = 1.0f / (hsel ? lsum1 : lsum0);
    __syncthreads();

    const int sh = hsel * 16;
    const char* __restrict__ hb = (const char*)h + head * 64 + cl * 16;
    float acc[8];
    #pragma unroll
    for (int c = 0; c < 8; ++c) acc[c] = 0.f;

    auto hw = [&](unsigned packed) -> float {
        union { unsigned short u; __half hh; } cv;
        cv.u = (unsigned short)(packed >> sh);
        return __half2float(cv.hh);
    };

    if (fast) {
        const uint2* __restrict__ row = &s_oe[wv][d * LDE];
        int k = 0;
        if (deg >= 8) {
            uint4 q0 = *(const uint4*)&row[0];
            uint4 q1 = *(const uint4*)&row[2];
            uint4 v0 = *(const uint4*)(hb + q0.x);
            uint4 v1 = *(const uint4*)(hb + q0.z);
            uint4 v2 = *(const uint4*)(hb + q1.x);
            uint4 v3 = *(const uint4*)(hb + q1.z);
            for (k = 4; k + 3 < deg; k += 4) {
                uint4 nq0 = *(const uint4*)&row[k];
                uint4 nq1 = *(const uint4*)&row[k + 2];
                uint4 nv0 = *(const uint4*)(hb + nq0.x);
                uint4 nv1 = *(const uint4*)(hb + nq0.z);
                uint4 nv2 = *(const uint4*)(hb + nq1.x);
                uint4 nv3 = *(const uint4*)(hb + nq1.z);
                fma8(acc, hw(q0.y), v0);
                fma8(acc, hw(q0.w), v1);
                fma8(acc, hw(q1.y), v2);
                fma8(acc, hw(q1.w), v3);
                q0 = nq0; q1 = nq1; v0 = nv0; v1 = nv1; v2 = nv2; v3 = nv3;
            }
            fma8(acc, hw(q0.y), v0);
            fma8(acc, hw(q0.w), v1);
            fma8(acc, hw(q1.y), v2);
            fma8(acc, hw(q1.w), v3);
        }
        for (; k < deg; ++k) {
            uint2 oe = row[k];
            uint4 v = *(const uint4*)(hb + oe.x);
            fma8(acc, hw(oe.y), v);
        }
    } else {
        const float adh = hsel ? adp.y : adp.x;
        for (int k = 0; k < deg; ++k) {
            int j = csr_src[start + k];
            float e = asrc[j * 8 + head] + adh;
            e = e > 0.f ? e : 0.2f * e;
            uint4 v = *(const uint4*)(hb + (size_t)j * 512);
            fma8(acc, __expf(e), v);
        }
    }

    union { __half h8[8]; uint4 u4; } pk;
    #pragma unroll
    for (int c = 0; c < 8; ++c) pk.h8[c] = __float2half(acc[c] * dinv);
    *(uint4*)&partial[((size_t)i * 8 + head) * 32 + cl * 8] = pk.u4;
}

// ---------------------------------------------------------------------------
// Merge heads: out = [relu](mean_h partial + bias); fp16 or fp32 output.
// ---------------------------------------------------------------------------
template <int CH, bool RELU, bool HALF_OUT>
__global__ __launch_bounds__(256) void merge_kernel(const __half* __restrict__ partial,
                                                    const float* __restrict__ bias,
                                                    void* __restrict__ out) {
    int flat = blockIdx.x * 256 + threadIdx.x;
    int i = flat / CH;
    int c = flat % CH;
    float s = 0.f;
    #pragma unroll
    for (int h8 = 0; h8 < 8; ++h8)
        s += __half2float(partial[((size_t)i * 8 + h8) * CH + c]);
    s = s * 0.125f + bias[c];
    if (RELU) s = fmaxf(s, 0.f);
    if (HALF_OUT) ((__half*)out)[flat] = __float2half(s);
    else          ((float*)out)[flat] = s;
}

// ---------------------------------------------------------------------------
// Launch
// ---------------------------------------------------------------------------
extern "C" void kernel_launch(void* const* d_in, const int* in_sizes, int n_in,
                              void* d_out, int out_size, void* d_ws, size_t ws_size,
                              hipStream_t stream) {
    const float* x   = (const float*)d_in[0];
    const int*   ei  = (const int*)d_in[1];
    const float* W1  = (const float*)d_in[2];
    const float* as1 = (const float*)d_in[3];
    const float* ad1 = (const float*)d_in[4];
    const float* b1  = (const float*)d_in[5];
    const float* W2  = (const float*)d_in[6];
    const float* as2 = (const float*)d_in[7];
    const float* ad2 = (const float*)d_in[8];
    const float* b2  = (const float*)d_in[9];

    const int n = N_NODES;
    const int e = E_EDGES;

    // ---- workspace layout ----
    char* w = (char*)d_ws;
    __half* partial = (__half*)w; w += (size_t)n * 8 * 64 * 2;  // 20.48 MB
    __half* h_buf = (__half*)w; w += (size_t)n * 512 * 2;       // 20.48 MB
    __half* y1h   = (__half*)w; w += (size_t)n * 64 * 2;        // 2.56 MB
    float* asrc   = (float*)w; w += (size_t)n * 8 * 4;
    float* adst   = (float*)w; w += (size_t)n * 8 * 4;
    int* deg       = (int*)w; w += (size_t)n * 4;
    int* row_start = (int*)w; w += (size_t)(n + 1) * 4;
    int* cursor    = (int*)w; w += (size_t)n * 4;
    int* csr_src   = (int*)w; w += (size_t)(e + n) * 4;

    // ---- CSR build (graph identical for both layers) ----
    init_deg_kernel<<<(n + 255) / 256, 256, 0, stream>>>(deg, n);
    count_deg_kernel<<<(e + 255) / 256, 256, 0, stream>>>(ei, e, deg);
    scan_kernel<<<1, 1024, 0, stream>>>(deg, row_start, cursor, n, e + n);
    scatter_kernel<<<(e + n + 255) / 256, 256, 0, stream>>>(ei, e, n, cursor, csr_src);

    const int mb = (n + 127) / 128;  // 157

    // ---- Layer 1 (cast + logits fused into GEMM, 128x128 tiles) ----
    gemm_kernel<64, float><<<dim3(mb, 4), 256, 0, stream>>>(
        x, W1, h_buf, as1, ad1, asrc, adst, n, 256, 512);
    aggregate1_kernel<<<(n / 32) * 8, 256, 0, stream>>>(h_buf, asrc, adst, row_start,
                                                        csr_src, partial);
    merge_kernel<64, true, true><<<n * 64 / 256, 256, 0, stream>>>(partial, b1, y1h);

    // ---- Layer 2 (fp16 A path) ----
    gemm_kernel<32, __half><<<dim3(mb, 2), 256, 0, stream>>>(
        y1h, W2, h_buf, as2, ad2, asrc, adst, n, 64, 256);
    aggregate2_kernel<<<(n / 32) * 4, 256, 0, stream>>>(h_buf, asrc, adst, row_start,
                                                        csr_src, partial);
    merge_kernel<32, false, false><<<n * 32 / 256, 256, 0, stream>>>(partial, b2, (float*)d_out);
}